// Round 12
// baseline (182.784 us; speedup 1.0000x reference)
//
#include <hip/hip_runtime.h>

// weighted_graph_conv, round 12:
//  - Wt transpose staging fixed: lane reads W[lane*64+f] (strided, 16KB L2-hot),
//    writes Wt[f*64+lane] consecutively -> ZERO bank conflicts (was 64-way,
//    6.6M conflict cycles = the counter's exact value)
//  - hist slice moved AFTER transform compute: atomics no longer drained by the
//    staging __syncthreads' implicit vmcnt(0)
//  - rest unchanged from R11 (scalarized gather, fused pipeline, no scanC)

#define F_DIM 64
#define TF 256  // T*F

__device__ __forceinline__ unsigned short f2bf(float x) {
  unsigned u = __float_as_uint(x);
  return (unsigned short)((u + 0x7FFF + ((u >> 16) & 1)) >> 16);  // RNE
}
__device__ __forceinline__ float bf2f(unsigned short b) {
  return __uint_as_float(((unsigned)b) << 16);
}
__device__ __forceinline__ void fma4(float4& a, float s, float4 w) {
  a.x += s * w.x; a.y += s * w.y; a.z += s * w.z; a.w += s * w.w;
}

__global__ __launch_bounds__(1024) void scanA_kernel(
    const int* __restrict__ cnt, int* __restrict__ off, int* __restrict__ bsum, int N) {
  __shared__ int wsum[16];
  int tid = threadIdx.x;
  int i = blockIdx.x * 1024 + tid;
  int v = (i < N) ? cnt[i] : 0;
  int lane = tid & 63;
  int incl = v;
  #pragma unroll
  for (int s = 1; s < 64; s <<= 1) {
    int t = __shfl_up(incl, s, 64);
    if (lane >= s) incl += t;
  }
  int w = tid >> 6;
  if (lane == 63) wsum[w] = incl;
  __syncthreads();
  if (w == 0) {
    int x = (lane < 16) ? wsum[lane] : 0;
    #pragma unroll
    for (int s = 1; s < 16; s <<= 1) {
      int t = __shfl_up(x, s, 64);
      if (lane >= s) x += t;
    }
    if (lane < 16) wsum[lane] = x;
  }
  __syncthreads();
  int wpre = (w == 0) ? 0 : wsum[w - 1];
  if (i < N) off[i] = wpre + incl - v;          // block-local exclusive
  if (tid == 1023) bsum[blockIdx.x] = wpre + incl;
}

// Exclusive scan of <=64 block totals in place (one wave).
__global__ __launch_bounds__(64) void scanB_kernel(int* __restrict__ bsum, int nb) {
  int lane = threadIdx.x;
  int v = (lane < nb) ? bsum[lane] : 0;
  int incl = v;
  #pragma unroll
  for (int s = 1; s < 64; s <<= 1) {
    int t = __shfl_up(incl, s, 64);
    if (lane >= s) incl += t;
  }
  if (lane < nb) bsum[lane] = incl - v;
}

// CSR record: x=src, y=(w1|w0) bf16 pair, z=(w3|w2) bf16 pair, w=0.
__global__ __launch_bounds__(256) void fill_kernel(
    const int* __restrict__ dst, const int* __restrict__ src,
    const float* __restrict__ ew, const int* __restrict__ off,
    const int* __restrict__ bsum, int* __restrict__ cnt,
    uint4* __restrict__ rec, int E) {
  int e = blockIdx.x * 256 + threadIdx.x;
  if (e < E) {
    int d = dst[e];
    int pos = off[d] + bsum[d >> 10] + atomicSub(&cnt[d], 1) - 1;
    unsigned w0 = f2bf(ew[e]),         w1 = f2bf(ew[E + e]);
    unsigned w2 = f2bf(ew[2 * E + e]), w3 = f2bf(ew[3 * E + e]);
    uint4 r;
    r.x = (unsigned)src[e];
    r.y = (w1 << 16) | w0;
    r.z = (w3 << 16) | w2;
    r.w = 0;
    rec[pos] = r;   // single scattered 16B store, cached (L2/L3)
  }
}

// Fused: transform tile + (post-compute) per-block histogram slice.
// Transform: nfb[row,:] = bf16(W @ nf[row,:]); 128 rows/block in LDS (49.3KB
// -> 3 blocks/CU); thread tile 4 rows x 8 outputs.
__global__ __launch_bounds__(256) void transform_hist_kernel(
    const float4* __restrict__ nf4, const float* __restrict__ W,
    unsigned short* __restrict__ nfb, int nrows,
    const int* __restrict__ dst, int* __restrict__ cnt, int E, int epb) {
  __shared__ float Wt[64 * 64];     // Wt[f*64+o] = W[o*64+f]  (16 KB)
  __shared__ float rows[128][65];   // 33.3 KB, +1 pad
  int tid = threadIdx.x;

  // Conflict-free transpose: lane o reads W[o][f] (strided 4B, 16KB L2-hot),
  // writes Wt[f*64 + o] with o = consecutive lanes -> linear, zero conflicts.
  #pragma unroll
  for (int i = tid; i < 4096; i += 256) {
    int o = i & 63, f = i >> 6;     // per-instruction: o = lane, f = const
    Wt[f * 64 + o] = W[o * 64 + f];
  }
  int rbase = blockIdx.x * 128;
  int nr = min(128, nrows - rbase);
  for (int i = tid; i < nr * 16; i += 256) {
    int r = i >> 4, q = i & 15;
    float4 v = nf4[(size_t)(rbase + r) * 16 + q];
    rows[r][q * 4 + 0] = v.x; rows[r][q * 4 + 1] = v.y;
    rows[r][q * 4 + 2] = v.z; rows[r][q * 4 + 3] = v.w;
  }
  __syncthreads();

  int oq = tid & 7;          // output chunk: o in [oq*8, oq*8+8)
  int r0 = (tid >> 3) * 4;   // 4 rows per thread
  float4 acc[4][2];
  #pragma unroll
  for (int j = 0; j < 4; ++j) {
    acc[j][0] = make_float4(0.f, 0.f, 0.f, 0.f);
    acc[j][1] = make_float4(0.f, 0.f, 0.f, 0.f);
  }
  const float4* Wt4 = (const float4*)Wt;  // Wt4[f*16 + o4]
  #pragma unroll 8
  for (int f = 0; f < 64; ++f) {
    float4 w0 = Wt4[f * 16 + oq * 2 + 0];   // 2-way bank alias: free
    float4 w1 = Wt4[f * 16 + oq * 2 + 1];
    #pragma unroll
    for (int j = 0; j < 4; ++j) {
      float rv = rows[r0 + j][f];           // broadcast groups: conflict-free
      fma4(acc[j][0], rv, w0);
      fma4(acc[j][1], rv, w1);
    }
  }
  int obase = oq * 8;
  #pragma unroll
  for (int j = 0; j < 4; ++j) {
    if (r0 + j < nr) {
      size_t rowoff = (size_t)(rbase + r0 + j) * F_DIM + obase;
      #pragma unroll
      for (int c = 0; c < 2; ++c) {
        float4 a = acc[j][c];
        ushort4 u = make_ushort4(f2bf(a.x), f2bf(a.y), f2bf(a.z), f2bf(a.w));
        *reinterpret_cast<ushort4*>(&nfb[rowoff + c * 4]) = u;
      }
    }
  }

  // --- histogram slice at the END: atomics issue post-barrier, latency
  // overlaps across blocks instead of stalling the staging sync ---
  {
    int e0 = blockIdx.x * epb;
    int e1 = min(e0 + epb, E);
    for (int e = e0 + tid; e < e1; e += 256) atomicAdd(&cnt[dst[e]], 1);
  }
}

// One wave per node; lane r: t=r>>4, q=r&15. 4-wide unrolled gather.
// n/beg/end wave-uniform via readfirstlane -> rec loads scalarize (s_load).
__global__ __launch_bounds__(256) void gather_bf16_kernel(
    const ushort4* __restrict__ nfb, const uint4* __restrict__ rec,
    const int* __restrict__ off, const int* __restrict__ bsum,
    const float4* __restrict__ bias4, float4* __restrict__ out4, int N, int E) {
  int idx = blockIdx.x * 256 + threadIdx.x;
  int n = idx >> 6;
  if (n >= N) return;
  n = __builtin_amdgcn_readfirstlane(n);   // provably uniform
  int r = idx & 63, t = r >> 4, q = r & 15;
  int wsel = t >> 1;            // 0: use rec.y, 1: use rec.z
  int wshift = (t & 1) << 4;    // 0 or 16
  int beg = off[n] + bsum[n >> 10];
  int end = (n + 1 < N) ? off[n + 1] + bsum[(n + 1) >> 10] : E;
  beg = __builtin_amdgcn_readfirstlane(beg);
  end = __builtin_amdgcn_readfirstlane(end);

  float4 acc = make_float4(0.f, 0.f, 0.f, 0.f);
  int p = beg;
  for (; p + 4 <= end; p += 4) {
    uint4 r0 = rec[p], r1 = rec[p + 1], r2 = rec[p + 2], r3 = rec[p + 3];
    float w0 = __uint_as_float(((wsel ? r0.z : r0.y) >> wshift) << 16);
    float w1 = __uint_as_float(((wsel ? r1.z : r1.y) >> wshift) << 16);
    float w2 = __uint_as_float(((wsel ? r2.z : r2.y) >> wshift) << 16);
    float w3 = __uint_as_float(((wsel ? r3.z : r3.y) >> wshift) << 16);
    ushort4 v0 = nfb[(size_t)r0.x * 64 + t * 16 + q];
    ushort4 v1 = nfb[(size_t)r1.x * 64 + t * 16 + q];
    ushort4 v2 = nfb[(size_t)r2.x * 64 + t * 16 + q];
    ushort4 v3 = nfb[(size_t)r3.x * 64 + t * 16 + q];
    acc.x += w0 * bf2f(v0.x) + w1 * bf2f(v1.x) + w2 * bf2f(v2.x) + w3 * bf2f(v3.x);
    acc.y += w0 * bf2f(v0.y) + w1 * bf2f(v1.y) + w2 * bf2f(v2.y) + w3 * bf2f(v3.y);
    acc.z += w0 * bf2f(v0.z) + w1 * bf2f(v1.z) + w2 * bf2f(v2.z) + w3 * bf2f(v3.z);
    acc.w += w0 * bf2f(v0.w) + w1 * bf2f(v1.w) + w2 * bf2f(v2.w) + w3 * bf2f(v3.w);
  }
  for (; p < end; ++p) {
    uint4 rr = rec[p];
    float w = __uint_as_float(((wsel ? rr.z : rr.y) >> wshift) << 16);
    ushort4 v = nfb[(size_t)rr.x * 64 + t * 16 + q];
    acc.x += w * bf2f(v.x); acc.y += w * bf2f(v.y);
    acc.z += w * bf2f(v.z); acc.w += w * bf2f(v.w);
  }
  float4 b = bias4[q];
  float4 res = make_float4(acc.x + b.x, acc.y + b.y, acc.z + b.z, acc.w + b.w);
  out4[(size_t)n * 64 + t * 16 + q] = res;
}

// ---- f32 fallback path (small ws) ----
__global__ __launch_bounds__(256) void hist_kernel(
    const int* __restrict__ dst, int* __restrict__ cnt, int E) {
  int e = blockIdx.x * 256 + threadIdx.x;
  if (e < E) atomicAdd(&cnt[dst[e]], 1);
}

__global__ __launch_bounds__(256) void gather_f32_kernel(
    const float4* __restrict__ nf4, const uint4* __restrict__ rec,
    const int* __restrict__ off, const int* __restrict__ bsum,
    float4* __restrict__ h4, int N, int E) {
  int idx = blockIdx.x * 256 + threadIdx.x;
  int n = idx >> 6;
  if (n >= N) return;
  int r = idx & 63, t = r >> 4, q = r & 15;
  int wsel = t >> 1;
  int wshift = (t & 1) << 4;
  int beg = off[n] + bsum[n >> 10];
  int end = (n + 1 < N) ? off[n + 1] + bsum[(n + 1) >> 10] : E;
  float4 acc = make_float4(0.f, 0.f, 0.f, 0.f);
  for (int p = beg; p < end; ++p) {
    uint4 rr = rec[p];
    float w = __uint_as_float(((wsel ? rr.z : rr.y) >> wshift) << 16);
    float4 v = nf4[(size_t)rr.x * 64 + t * 16 + q];
    acc.x += w * v.x; acc.y += w * v.y; acc.z += w * v.z; acc.w += w * v.w;
  }
  h4[(size_t)n * 64 + t * 16 + q] = acc;
}

__global__ __launch_bounds__(256) void linear_kernel(
    float* __restrict__ h, const float* __restrict__ W,
    const float* __restrict__ bias, int nrows) {
  __shared__ float Wt[64 * 65];
  __shared__ float rows[4][64];
  int tid = threadIdx.x;
  for (int i = tid; i < 4096; i += 256) Wt[(i & 63) * 65 + (i >> 6)] = W[i];
  int rr = tid >> 6, o = tid & 63;
  float b = bias[o];
  int rbase = blockIdx.x * 32;
  for (int r0 = 0; r0 < 32; r0 += 4) {
    int row = rbase + r0 + rr;
    __syncthreads();
    if (row < nrows) rows[rr][o] = h[(size_t)row * F_DIM + o];
    __syncthreads();
    if (row < nrows) {
      float acc = b;
      #pragma unroll
      for (int f = 0; f < 64; ++f) acc += rows[rr][f] * Wt[f * 65 + o];
      h[(size_t)row * F_DIM + o] = acc;
    }
  }
}

extern "C" void kernel_launch(void* const* d_in, const int* in_sizes, int n_in,
                              void* d_out, int out_size, void* d_ws, size_t ws_size,
                              hipStream_t stream) {
  const float* nf   = (const float*)d_in[0];
  const float* ew   = (const float*)d_in[1];
  const int*   src  = (const int*)d_in[2];
  const int*   dst  = (const int*)d_in[3];
  const float* W    = (const float*)d_in[4];
  const float* bias = (const float*)d_in[5];
  float* out = (float*)d_out;

  int E = in_sizes[2];
  int N = out_size / TF;
  int nrows = out_size / F_DIM;   // N*T
  int nfelems = nrows * F_DIM;

  // ws layout: [cnt N][off N+1][bsum 64] | rec uint4[E] | nfb (512B-aligned)
  char* wsb = (char*)d_ws;
  int* cnt  = (int*)wsb;
  int* off  = cnt + N;
  int* bsum = off + (N + 1);
  size_t ofs = ((size_t)(2 * N + 1 + 64) * 4 + 15) & ~(size_t)15;
  uint4* rec = (uint4*)(wsb + ofs);           ofs += (size_t)E * 16;
  ofs = (ofs + 511) & ~(size_t)511;           // row-align nfb: 4 exact lines/row
  unsigned short* nfb = (unsigned short*)(wsb + ofs);
  size_t need_bf16 = ofs + (size_t)nfelems * 2;
  bool use_bf16 = ws_size >= need_bf16;

  (void)hipMemsetAsync(cnt, 0, (size_t)N * sizeof(int), stream);

  int eblk = (E + 255) / 256;
  int sblk = (N + 1023) / 1024;

  if (use_bf16) {
    int tblocks = (nrows + 127) / 128;
    int epb = (E + tblocks - 1) / tblocks;
    transform_hist_kernel<<<tblocks, 256, 0, stream>>>(
        (const float4*)nf, W, nfb, nrows, dst, cnt, E, epb);
    scanA_kernel<<<sblk, 1024, 0, stream>>>(cnt, off, bsum, N);
    scanB_kernel<<<1, 64, 0, stream>>>(bsum, sblk);
    fill_kernel<<<eblk, 256, 0, stream>>>(dst, src, ew, off, bsum, cnt, rec, E);
    gather_bf16_kernel<<<(N * 64 + 255) / 256, 256, 0, stream>>>(
        (const ushort4*)nfb, rec, off, bsum, (const float4*)bias,
        (float4*)out, N, E);
  } else {
    hist_kernel<<<eblk, 256, 0, stream>>>(dst, cnt, E);
    scanA_kernel<<<sblk, 1024, 0, stream>>>(cnt, off, bsum, N);
    scanB_kernel<<<1, 64, 0, stream>>>(bsum, sblk);
    fill_kernel<<<eblk, 256, 0, stream>>>(dst, src, ew, off, bsum, cnt, rec, E);
    gather_f32_kernel<<<(N * 64 + 255) / 256, 256, 0, stream>>>(
        (const float4*)nf, rec, off, bsum, (float4*)out, N, E);
    linear_kernel<<<(nrows + 31) / 32, 256, 0, stream>>>(out, W, bias, nrows);
  }
}

// Round 13
// 160.246 us; speedup vs baseline: 1.1406x; 1.1406x over previous
//
#include <hip/hip_runtime.h>

// weighted_graph_conv, round 13: transform on the MATRIX CORES.
//  - R12 post-mortem: transform was LDS-issue-bound (12K LDS-pipe cyc/block vs
//    4K VALU), not conflict-bound. Fix: mfma_f32_16x16x32_bf16, zero LDS.
//  - D[o][r] tiles: A = W (full 64x64 in 8 frags/wave, loaded once),
//    B = nf rows (8 contiguous f32 -> bf16 per lane). D reg-dim walks o ->
//    lane stores 4 consecutive o as one ushort4. No LDS transpose needed.
//  - hist grid-strided at kernel end (fused, as before).
//  - fill/scan/gather unchanged from R12.

#define F_DIM 64
#define TF 256  // T*F

typedef __attribute__((ext_vector_type(8))) short bf16x8;
typedef __attribute__((ext_vector_type(4))) float f32x4;
union frag_u { bf16x8 v; unsigned short s[8]; };

__device__ __forceinline__ unsigned short f2bf(float x) {
  unsigned u = __float_as_uint(x);
  return (unsigned short)((u + 0x7FFF + ((u >> 16) & 1)) >> 16);  // RNE
}
__device__ __forceinline__ float bf2f(unsigned short b) {
  return __uint_as_float(((unsigned)b) << 16);
}

__global__ __launch_bounds__(1024) void scanA_kernel(
    const int* __restrict__ cnt, int* __restrict__ off, int* __restrict__ bsum, int N) {
  __shared__ int wsum[16];
  int tid = threadIdx.x;
  int i = blockIdx.x * 1024 + tid;
  int v = (i < N) ? cnt[i] : 0;
  int lane = tid & 63;
  int incl = v;
  #pragma unroll
  for (int s = 1; s < 64; s <<= 1) {
    int t = __shfl_up(incl, s, 64);
    if (lane >= s) incl += t;
  }
  int w = tid >> 6;
  if (lane == 63) wsum[w] = incl;
  __syncthreads();
  if (w == 0) {
    int x = (lane < 16) ? wsum[lane] : 0;
    #pragma unroll
    for (int s = 1; s < 16; s <<= 1) {
      int t = __shfl_up(x, s, 64);
      if (lane >= s) x += t;
    }
    if (lane < 16) wsum[lane] = x;
  }
  __syncthreads();
  int wpre = (w == 0) ? 0 : wsum[w - 1];
  if (i < N) off[i] = wpre + incl - v;          // block-local exclusive
  if (tid == 1023) bsum[blockIdx.x] = wpre + incl;
}

__global__ __launch_bounds__(64) void scanB_kernel(int* __restrict__ bsum, int nb) {
  int lane = threadIdx.x;
  int v = (lane < nb) ? bsum[lane] : 0;
  int incl = v;
  #pragma unroll
  for (int s = 1; s < 64; s <<= 1) {
    int t = __shfl_up(incl, s, 64);
    if (lane >= s) incl += t;
  }
  if (lane < nb) bsum[lane] = incl - v;
}

// CSR record: x=src, y=(w1|w0) bf16 pair, z=(w3|w2) bf16 pair, w=0.
__global__ __launch_bounds__(256) void fill_kernel(
    const int* __restrict__ dst, const int* __restrict__ src,
    const float* __restrict__ ew, const int* __restrict__ off,
    const int* __restrict__ bsum, int* __restrict__ cnt,
    uint4* __restrict__ rec, int E) {
  int e = blockIdx.x * 256 + threadIdx.x;
  if (e < E) {
    int d = dst[e];
    int pos = off[d] + bsum[d >> 10] + atomicSub(&cnt[d], 1) - 1;
    unsigned w0 = f2bf(ew[e]),         w1 = f2bf(ew[E + e]);
    unsigned w2 = f2bf(ew[2 * E + e]), w3 = f2bf(ew[3 * E + e]);
    uint4 r;
    r.x = (unsigned)src[e];
    r.y = (w1 << 16) | w0;
    r.z = (w3 << 16) | w2;
    r.w = 0;
    rec[pos] = r;
  }
}

// MFMA transform + fused grid-stride histogram.
// Per wave: A-frags a[ot][kh] = W[ot*16+(l&15)][kh*32+(l>>4)*8 + 0..7] (bf16),
// loop 16-row tiles: B-frags from nf rows, 8 mfmas -> D[o][r] 16x64,
// lane stores nfb[r][ot*16+(l>>4)*4 .. +3] as ushort4.
__global__ __launch_bounds__(256) void transform_hist_kernel(
    const float4* __restrict__ nf4, const float* __restrict__ W,
    unsigned short* __restrict__ nfb, int nrows,
    const int* __restrict__ dst, int* __restrict__ cnt, int E) {
  int lane = threadIdx.x & 63;
  int l15 = lane & 15, lg = lane >> 4;
  int wid = (blockIdx.x * 256 + threadIdx.x) >> 6;
  int nw = (gridDim.x * 256) >> 6;

  // A = W, staged once per wave (16 KB array, L2-hot after first blocks)
  frag_u a[4][2];
  #pragma unroll
  for (int ot = 0; ot < 4; ++ot) {
    #pragma unroll
    for (int kh = 0; kh < 2; ++kh) {
      const float* wp = W + (ot * 16 + l15) * 64 + kh * 32 + lg * 8;
      float4 v0 = *reinterpret_cast<const float4*>(wp);
      float4 v1 = *reinterpret_cast<const float4*>(wp + 4);
      a[ot][kh].s[0] = f2bf(v0.x); a[ot][kh].s[1] = f2bf(v0.y);
      a[ot][kh].s[2] = f2bf(v0.z); a[ot][kh].s[3] = f2bf(v0.w);
      a[ot][kh].s[4] = f2bf(v1.x); a[ot][kh].s[5] = f2bf(v1.y);
      a[ot][kh].s[6] = f2bf(v1.z); a[ot][kh].s[7] = f2bf(v1.w);
    }
  }

  int ntiles = (nrows + 15) >> 4;
  for (int tile = wid; tile < ntiles; tile += nw) {
    int r = tile * 16 + l15;
    int rc = min(r, nrows - 1);               // clamp loads; stores guarded
    const float4* bp = nf4 + (size_t)rc * 16 + lg * 2;
    float4 v0 = bp[0], v1 = bp[1];            // f = lg*8 .. lg*8+7
    float4 v2 = bp[8], v3 = bp[9];            // f = 32+lg*8 .. +7
    frag_u b0, b1;
    b0.s[0] = f2bf(v0.x); b0.s[1] = f2bf(v0.y);
    b0.s[2] = f2bf(v0.z); b0.s[3] = f2bf(v0.w);
    b0.s[4] = f2bf(v1.x); b0.s[5] = f2bf(v1.y);
    b0.s[6] = f2bf(v1.z); b0.s[7] = f2bf(v1.w);
    b1.s[0] = f2bf(v2.x); b1.s[1] = f2bf(v2.y);
    b1.s[2] = f2bf(v2.z); b1.s[3] = f2bf(v2.w);
    b1.s[4] = f2bf(v3.x); b1.s[5] = f2bf(v3.y);
    b1.s[6] = f2bf(v3.z); b1.s[7] = f2bf(v3.w);

    f32x4 acc[4];
    #pragma unroll
    for (int ot = 0; ot < 4; ++ot) {
      f32x4 z = {0.f, 0.f, 0.f, 0.f};
      acc[ot] = __builtin_amdgcn_mfma_f32_16x16x32_bf16(a[ot][0].v, b0.v, z, 0, 0, 0);
      acc[ot] = __builtin_amdgcn_mfma_f32_16x16x32_bf16(a[ot][1].v, b1.v, acc[ot], 0, 0, 0);
    }
    if (r < nrows) {
      #pragma unroll
      for (int ot = 0; ot < 4; ++ot) {
        ushort4 u = make_ushort4(f2bf(acc[ot][0]), f2bf(acc[ot][1]),
                                 f2bf(acc[ot][2]), f2bf(acc[ot][3]));
        *reinterpret_cast<ushort4*>(
            &nfb[(size_t)r * F_DIM + ot * 16 + lg * 4]) = u;
      }
    }
  }

  // fused histogram (grid-stride)
  int gtid = blockIdx.x * 256 + threadIdx.x;
  int gsz = gridDim.x * 256;
  for (int e = gtid; e < E; e += gsz) atomicAdd(&cnt[dst[e]], 1);
}

// One wave per node; lane r: t=r>>4, q=r&15. 4-wide unrolled gather.
// n/beg/end wave-uniform via readfirstlane -> rec loads scalarize (s_load).
__global__ __launch_bounds__(256) void gather_bf16_kernel(
    const ushort4* __restrict__ nfb, const uint4* __restrict__ rec,
    const int* __restrict__ off, const int* __restrict__ bsum,
    const float4* __restrict__ bias4, float4* __restrict__ out4, int N, int E) {
  int idx = blockIdx.x * 256 + threadIdx.x;
  int n = idx >> 6;
  if (n >= N) return;
  n = __builtin_amdgcn_readfirstlane(n);
  int r = idx & 63, t = r >> 4, q = r & 15;
  int wsel = t >> 1;
  int wshift = (t & 1) << 4;
  int beg = off[n] + bsum[n >> 10];
  int end = (n + 1 < N) ? off[n + 1] + bsum[(n + 1) >> 10] : E;
  beg = __builtin_amdgcn_readfirstlane(beg);
  end = __builtin_amdgcn_readfirstlane(end);

  float4 acc = make_float4(0.f, 0.f, 0.f, 0.f);
  int p = beg;
  for (; p + 4 <= end; p += 4) {
    uint4 r0 = rec[p], r1 = rec[p + 1], r2 = rec[p + 2], r3 = rec[p + 3];
    float w0 = __uint_as_float(((wsel ? r0.z : r0.y) >> wshift) << 16);
    float w1 = __uint_as_float(((wsel ? r1.z : r1.y) >> wshift) << 16);
    float w2 = __uint_as_float(((wsel ? r2.z : r2.y) >> wshift) << 16);
    float w3 = __uint_as_float(((wsel ? r3.z : r3.y) >> wshift) << 16);
    ushort4 v0 = nfb[(size_t)r0.x * 64 + t * 16 + q];
    ushort4 v1 = nfb[(size_t)r1.x * 64 + t * 16 + q];
    ushort4 v2 = nfb[(size_t)r2.x * 64 + t * 16 + q];
    ushort4 v3 = nfb[(size_t)r3.x * 64 + t * 16 + q];
    acc.x += w0 * bf2f(v0.x) + w1 * bf2f(v1.x) + w2 * bf2f(v2.x) + w3 * bf2f(v3.x);
    acc.y += w0 * bf2f(v0.y) + w1 * bf2f(v1.y) + w2 * bf2f(v2.y) + w3 * bf2f(v3.y);
    acc.z += w0 * bf2f(v0.z) + w1 * bf2f(v1.z) + w2 * bf2f(v2.z) + w3 * bf2f(v3.z);
    acc.w += w0 * bf2f(v0.w) + w1 * bf2f(v1.w) + w2 * bf2f(v2.w) + w3 * bf2f(v3.w);
  }
  for (; p < end; ++p) {
    uint4 rr = rec[p];
    float w = __uint_as_float(((wsel ? rr.z : rr.y) >> wshift) << 16);
    ushort4 v = nfb[(size_t)rr.x * 64 + t * 16 + q];
    acc.x += w * bf2f(v.x); acc.y += w * bf2f(v.y);
    acc.z += w * bf2f(v.z); acc.w += w * bf2f(v.w);
  }
  float4 b = bias4[q];
  float4 res = make_float4(acc.x + b.x, acc.y + b.y, acc.z + b.z, acc.w + b.w);
  out4[(size_t)n * 64 + t * 16 + q] = res;
}

// ---- f32 fallback path (small ws) ----
__global__ __launch_bounds__(256) void hist_kernel(
    const int* __restrict__ dst, int* __restrict__ cnt, int E) {
  int e = blockIdx.x * 256 + threadIdx.x;
  if (e < E) atomicAdd(&cnt[dst[e]], 1);
}

__global__ __launch_bounds__(256) void gather_f32_kernel(
    const float4* __restrict__ nf4, const uint4* __restrict__ rec,
    const int* __restrict__ off, const int* __restrict__ bsum,
    float4* __restrict__ h4, int N, int E) {
  int idx = blockIdx.x * 256 + threadIdx.x;
  int n = idx >> 6;
  if (n >= N) return;
  int r = idx & 63, t = r >> 4, q = r & 15;
  int wsel = t >> 1;
  int wshift = (t & 1) << 4;
  int beg = off[n] + bsum[n >> 10];
  int end = (n + 1 < N) ? off[n + 1] + bsum[(n + 1) >> 10] : E;
  float4 acc = make_float4(0.f, 0.f, 0.f, 0.f);
  for (int p = beg; p < end; ++p) {
    uint4 rr = rec[p];
    float w = __uint_as_float(((wsel ? rr.z : rr.y) >> wshift) << 16);
    float4 v = nf4[(size_t)rr.x * 64 + t * 16 + q];
    acc.x += w * v.x; acc.y += w * v.y; acc.z += w * v.z; acc.w += w * v.w;
  }
  h4[(size_t)n * 64 + t * 16 + q] = acc;
}

__global__ __launch_bounds__(256) void linear_kernel(
    float* __restrict__ h, const float* __restrict__ W,
    const float* __restrict__ bias, int nrows) {
  __shared__ float Wt[64 * 65];
  __shared__ float rows[4][64];
  int tid = threadIdx.x;
  for (int i = tid; i < 4096; i += 256) Wt[(i & 63) * 65 + (i >> 6)] = W[i];
  int rr = tid >> 6, o = tid & 63;
  float b = bias[o];
  int rbase = blockIdx.x * 32;
  for (int r0 = 0; r0 < 32; r0 += 4) {
    int row = rbase + r0 + rr;
    __syncthreads();
    if (row < nrows) rows[rr][o] = h[(size_t)row * F_DIM + o];
    __syncthreads();
    if (row < nrows) {
      float acc = b;
      #pragma unroll
      for (int f = 0; f < 64; ++f) acc += rows[rr][f] * Wt[f * 65 + o];
      h[(size_t)row * F_DIM + o] = acc;
    }
  }
}

extern "C" void kernel_launch(void* const* d_in, const int* in_sizes, int n_in,
                              void* d_out, int out_size, void* d_ws, size_t ws_size,
                              hipStream_t stream) {
  const float* nf   = (const float*)d_in[0];
  const float* ew   = (const float*)d_in[1];
  const int*   src  = (const int*)d_in[2];
  const int*   dst  = (const int*)d_in[3];
  const float* W    = (const float*)d_in[4];
  const float* bias = (const float*)d_in[5];
  float* out = (float*)d_out;

  int E = in_sizes[2];
  int N = out_size / TF;
  int nrows = out_size / F_DIM;   // N*T
  int nfelems = nrows * F_DIM;

  // ws layout: [cnt N][off N+1][bsum 64] | rec uint4[E] | nfb (512B-aligned)
  char* wsb = (char*)d_ws;
  int* cnt  = (int*)wsb;
  int* off  = cnt + N;
  int* bsum = off + (N + 1);
  size_t ofs = ((size_t)(2 * N + 1 + 64) * 4 + 15) & ~(size_t)15;
  uint4* rec = (uint4*)(wsb + ofs);           ofs += (size_t)E * 16;
  ofs = (ofs + 511) & ~(size_t)511;
  unsigned short* nfb = (unsigned short*)(wsb + ofs);
  size_t need_bf16 = ofs + (size_t)nfelems * 2;
  bool use_bf16 = ws_size >= need_bf16;

  (void)hipMemsetAsync(cnt, 0, (size_t)N * sizeof(int), stream);

  int eblk = (E + 255) / 256;
  int sblk = (N + 1023) / 1024;

  if (use_bf16) {
    transform_hist_kernel<<<1024, 256, 0, stream>>>(
        (const float4*)nf, W, nfb, nrows, dst, cnt, E);
    scanA_kernel<<<sblk, 1024, 0, stream>>>(cnt, off, bsum, N);
    scanB_kernel<<<1, 64, 0, stream>>>(bsum, sblk);
    fill_kernel<<<eblk, 256, 0, stream>>>(dst, src, ew, off, bsum, cnt, rec, E);
    gather_bf16_kernel<<<(N * 64 + 255) / 256, 256, 0, stream>>>(
        (const ushort4*)nfb, rec, off, bsum, (const float4*)bias,
        (float4*)out, N, E);
  } else {
    hist_kernel<<<eblk, 256, 0, stream>>>(dst, cnt, E);
    scanA_kernel<<<sblk, 1024, 0, stream>>>(cnt, off, bsum, N);
    scanB_kernel<<<1, 64, 0, stream>>>(bsum, sblk);
    fill_kernel<<<eblk, 256, 0, stream>>>(dst, src, ew, off, bsum, cnt, rec, E);
    gather_f32_kernel<<<(N * 64 + 255) / 256, 256, 0, stream>>>(
        (const float4*)nf, rec, off, bsum, (float4*)out, N, E);
    linear_kernel<<<(nrows + 31) / 32, 256, 0, stream>>>(out, W, bias, nrows);
  }
}